// Round 4
// baseline (8780.464 us; speedup 1.0000x reference)
//
#include <hip/hip_runtime.h>

#define B_    128
#define T_    1024
#define I_    64
#define H_    256
#define DEC_  128
#define C_    64
#define NWG   128          // 64 unit-slices x 2 sample halves
#define KTOT  320          // K = H (256) + I (64)
#define LDK   328          // padded LDS stride (ushorts), init staging only
#define STEPS (T_ + DEC_)

typedef short bf16x8 __attribute__((ext_vector_type(8)));
typedef float f32x4  __attribute__((ext_vector_type(4)));
typedef unsigned u32x4 __attribute__((ext_vector_type(4)));
typedef unsigned long long u64;

#define SCOPE_AGENT __HIP_MEMORY_SCOPE_AGENT

__device__ __forceinline__ f32x4 mf(bf16x8 a, bf16x8 b, f32x4 c) {
  return __builtin_amdgcn_mfma_f32_16x16x32_bf16(a, b, c, 0, 0, 0);
}

// L2-cacheable, L1-bypassing 16B load (freshness guaranteed by per-step acquire fence)
__device__ __forceinline__ u32x4 load16_l2(const void* p) {
  u32x4 r;
  asm volatile("global_load_dwordx4 %0, %1, off sc0" : "=v"(r) : "v"(p) : "memory");
  return r;
}
// coherence-point 16B store (write-through past per-XCD L2)
__device__ __forceinline__ void store16_coh(void* p, u32x4 v) {
  asm volatile("global_store_dwordx4 %0, %1, off sc0 sc1" :: "v"(p), "v"(v) : "memory");
}

// round-to-nearest-even split of f32 into bf16 hi + bf16 lo (v ~= hi + lo)
__device__ __forceinline__ void bf16_split(float v, unsigned short& hi, unsigned short& lo) {
  unsigned u = __float_as_uint(v);
  unsigned r = (u + 0x7fffu + ((u >> 16) & 1u)) & 0xffff0000u;
  hi = (unsigned short)(r >> 16);
  float fl = v - __uint_as_float(r);
  unsigned u2 = __float_as_uint(fl);
  unsigned r2 = (u2 + 0x7fffu + ((u2 >> 16) & 1u)) & 0xffff0000u;
  lo = (unsigned short)(r2 >> 16);
}

__device__ __forceinline__ float sigm(float v) { return 1.0f / (1.0f + __expf(-v)); }
__device__ __forceinline__ float tanh_(float v) {
  float e = __expf(-2.0f * fabsf(v));
  float t = (1.0f - e) / (1.0f + e);
  return (v >= 0.0f) ? t : -t;
}

// x (f32) -> bf16 hi/lo planes
__global__ __launch_bounds__(256) void xsplit_k(const float* __restrict__ x,
                                                unsigned short* __restrict__ xh,
                                                unsigned short* __restrict__ xl, int n4) {
  const int i = blockIdx.x * 256 + threadIdx.x;
  if (i >= n4) return;
  const float4 v = ((const float4*)x)[i];
  unsigned short h[4], l[4];
  bf16_split(v.x, h[0], l[0]);
  bf16_split(v.y, h[1], l[1]);
  bf16_split(v.z, h[2], l[2]);
  bf16_split(v.w, h[3], l[3]);
  uint2 uh, ul;
  uh.x = (unsigned)h[0] | ((unsigned)h[1] << 16);
  uh.y = (unsigned)h[2] | ((unsigned)h[3] << 16);
  ul.x = (unsigned)l[0] | ((unsigned)l[1] << 16);
  ul.y = (unsigned)l[2] | ((unsigned)l[3] << 16);
  ((uint2*)xh)[i] = uh;
  ((uint2*)xl)[i] = ul;
}

// Exchange layout (per parity, 128 KB): chunk(u, s) = 16 B at ((u*128 + s)*16):
//   bytes 0-7 hi bf16 of units u*4..u*4+3, bytes 8-15 lo. One writer WG per chunk.
// Protocol: writer sc1-stores payload, vmcnt(0), sc1-stores flag; reader sc1-polls flags,
// then acquire-fence (buffer_inv) and sc0-loads payload (L2 dedups the 64-reader broadcast).
__global__ __launch_bounds__(256, 1) void rnn4(
    const float* __restrict__ x,
    const unsigned short* __restrict__ x_hi,
    const unsigned short* __restrict__ x_lo,
    const int use_xs,
    const int* __restrict__ lengths,
    const float* __restrict__ W_ih, const float* __restrict__ W_hh,
    const float* __restrict__ b_ih, const float* __restrict__ b_hh,
    char* __restrict__ arrb,
    char* __restrict__ hxc,
    char* __restrict__ decb)
{
  __shared__ unsigned short Whi[16][LDK];   // init staging only
  __shared__ unsigned short Wlo[16][LDK];

  const int tid  = threadIdx.x;
  const int g    = blockIdx.x;
  const int uo   = g >> 1;
  const int sh   = g & 1;
  const int j0   = uo * 4;
  const int wave = tid >> 6;
  const int lane = tid & 63;
  const int q4   = lane >> 4;
  const int n15  = lane & 15;
  const int s    = sh * 64 + wave * 16 + n15;

  // ---- init: stage split weights into LDS, then lift fragments into VGPRs ----
  for (int e = tid; e < 16 * KTOT; e += 256) {
    const int row = e / KTOT;
    const int k   = e - row * KTOT;
    const int grow = (row >> 2) * H_ + j0 + (row & 3);
    const float v = (k < H_) ? W_hh[grow * H_ + k] : W_ih[grow * I_ + (k - H_)];
    unsigned short h16, l16; bf16_split(v, h16, l16);
    Whi[row][k] = h16; Wlo[row][k] = l16;
  }
  __syncthreads();

  bf16x8 Ah[10], Al[10];                 // weight fragments, resident in VGPRs
  #pragma unroll
  for (int kh = 0; kh < 8; ++kh) {
    const int k0 = kh * 32 + q4 * 8;
    Ah[kh] = *(const bf16x8*)&Whi[n15][k0];
    Al[kh] = *(const bf16x8*)&Wlo[n15][k0];
  }
  #pragma unroll
  for (int kx = 0; kx < 2; ++kx) {
    const int k0 = H_ + kx * 32 + q4 * 8;
    Ah[8 + kx] = *(const bf16x8*)&Whi[n15][k0];
    Al[8 + kx] = *(const bf16x8*)&Wlo[n15][k0];
  }
  float bias4[4];
  #pragma unroll
  for (int e = 0; e < 4; ++e) {
    const int grow = q4 * H_ + j0 + e;   // gate = q4, unit = e
    bias4[e] = b_ih[grow] + b_hh[grow];
  }

  const int len_s = lengths[s];

  // zero our slice of parity-0 h (one 16B chunk per sample)
  if (tid < 64) {
    const int sz = sh * 64 + tid;
    u32x4 z; z.x = 0u; z.y = 0u; z.z = 0u; z.w = 0u;
    store16_coh(hxc + (((size_t)uo * 128 + sz) << 4), z);
  }

  // ---- init barrier ----
  asm volatile("s_waitcnt vmcnt(0)" ::: "memory");
  __syncthreads();
  if (tid == 0)
    __hip_atomic_store((unsigned*)(arrb + (size_t)(sh * 64 + uo) * 128), 1u,
                       __ATOMIC_RELAXED, SCOPE_AGENT);
  if (tid < 16) {
    const unsigned* f0 = (const unsigned*)(arrb + (size_t)(sh * 64 + tid * 4 + 0) * 128);
    const unsigned* f1 = (const unsigned*)(arrb + (size_t)(sh * 64 + tid * 4 + 1) * 128);
    const unsigned* f2 = (const unsigned*)(arrb + (size_t)(sh * 64 + tid * 4 + 2) * 128);
    const unsigned* f3 = (const unsigned*)(arrb + (size_t)(sh * 64 + tid * 4 + 3) * 128);
    bool ok;
    do {
      unsigned a = __hip_atomic_load(f0, __ATOMIC_RELAXED, SCOPE_AGENT);
      unsigned b = __hip_atomic_load(f1, __ATOMIC_RELAXED, SCOPE_AGENT);
      unsigned c = __hip_atomic_load(f2, __ATOMIC_RELAXED, SCOPE_AGENT);
      unsigned d = __hip_atomic_load(f3, __ATOMIC_RELAXED, SCOPE_AGENT);
      ok = (a >= 1u) & (b >= 1u) & (c >= 1u) & (d >= 1u);
    } while (!__all((int)ok));
  }
  __syncthreads();
  __builtin_amdgcn_fence(__ATOMIC_ACQUIRE, "agent");   // invalidate L1/L2 before first h read

  // x-part gate prefetch (independent of h); a0 seeded with bias
  auto xpart = [&](int t, f32x4& a0, f32x4& a1, f32x4& a2) {
    #pragma unroll
    for (int e = 0; e < 4; ++e) { a0[e] = bias4[e]; a1[e] = 0.f; a2[e] = 0.f; }
    if (t >= T_) return;
    #pragma unroll
    for (int kx = 0; kx < 2; ++kx) {
      bf16x8 bh, bl;
      if (use_xs) {
        const int xo = (s * T_ + t) * I_ + kx * 32 + q4 * 8;
        bh = *(const bf16x8*)(x_hi + xo);
        bl = *(const bf16x8*)(x_lo + xo);
      } else {
        const float* xp = x + ((size_t)s * T_ + t) * I_ + kx * 32 + q4 * 8;
        const float4 xa = *(const float4*)xp;
        const float4 xb = *(const float4*)(xp + 4);
        union { bf16x8 v; unsigned short u[8]; } bxh, bxl;
        float xv[8] = {xa.x, xa.y, xa.z, xa.w, xb.x, xb.y, xb.z, xb.w};
        #pragma unroll
        for (int e2 = 0; e2 < 8; ++e2) bf16_split(xv[e2], bxh.u[e2], bxl.u[e2]);
        bh = bxh.v; bl = bxl.v;
      }
      a0 = mf(Ah[8 + kx], bh, a0);
      a1 = mf(Ah[8 + kx], bl, a1);
      a2 = mf(Al[8 + kx], bh, a2);
    }
  };

  f32x4 xa0, xa1, xa2;
  xpart(0, xa0, xa1, xa2);

  float c_st[4] = {0.f, 0.f, 0.f, 0.f};
  float h_st[4] = {0.f, 0.f, 0.f, 0.f};

  for (int t = 0; t < STEPS; ++t) {
    const int p = t & 1;
    const char* rdc = hxc + (size_t)p * 131072;
    char*       wrc = hxc + (size_t)(p ^ 1) * 131072;

    // issue all 16 L2-cached 16B loads of h(t-1)
    u32x4 d0,d1,d2,d3,d4,d5,d6,d7,d8,d9,d10,d11,d12,d13,d14,d15;
#define LD_KH(i, DA, DB) { \
    const char* _b = rdc + (((size_t)(((i) * 8 + (q4 << 1)) * 128 + s)) << 4); \
    DA = load16_l2(_b); DB = load16_l2(_b + 2048); }
    LD_KH(0, d0,  d1)  LD_KH(1, d2,  d3)  LD_KH(2, d4,  d5)  LD_KH(3, d6,  d7)
    LD_KH(4, d8,  d9)  LD_KH(5, d10, d11) LD_KH(6, d12, d13) LD_KH(7, d14, d15)
#undef LD_KH

    asm volatile("s_waitcnt vmcnt(0)"
      : "+v"(d0),"+v"(d1),"+v"(d2),"+v"(d3),"+v"(d4),"+v"(d5),"+v"(d6),"+v"(d7),
        "+v"(d8),"+v"(d9),"+v"(d10),"+v"(d11),"+v"(d12),"+v"(d13),"+v"(d14),"+v"(d15)
      :: "memory");

    f32x4 a0 = xa0, a1 = xa1, a2 = xa2;
#define MM_KH(i, DA, DB) { \
    union { u32x4 q; bf16x8 v; } _h, _l; \
    _h.q.x = DA.x; _h.q.y = DA.y; _h.q.z = DB.x; _h.q.w = DB.y; \
    _l.q.x = DA.z; _l.q.y = DA.w; _l.q.z = DB.z; _l.q.w = DB.w; \
    a0 = mf(Ah[i], _h.v, a0); a1 = mf(Ah[i], _l.v, a1); a2 = mf(Al[i], _h.v, a2); }
    MM_KH(0, d0,  d1)  MM_KH(1, d2,  d3)  MM_KH(2, d4,  d5)  MM_KH(3, d6,  d7)
    MM_KH(4, d8,  d9)  MM_KH(5, d10, d11) MM_KH(6, d12, d13) MM_KH(7, d14, d15)
#undef MM_KH

    // gate combine: gather i,f,g,o across quads via shfl_xor
    unsigned short ph[4], plo[4];
    const bool update = (t < T_) ? (t < len_s) : true;
    #pragma unroll
    for (int e = 0; e < 4; ++e) {
      const float v0 = a0[e] + a1[e] + a2[e];
      const float v1 = __shfl_xor(v0, 16, 64);
      const float v2 = __shfl_xor(v0, 32, 64);
      const float v3 = __shfl_xor(v1, 32, 64);
      const float ig = (q4 == 0) ? v0 : (q4 == 1) ? v1 : (q4 == 2) ? v2 : v3;
      const float fg = (q4 == 1) ? v0 : (q4 == 0) ? v1 : (q4 == 3) ? v2 : v3;
      const float gg = (q4 == 2) ? v0 : (q4 == 3) ? v1 : (q4 == 0) ? v2 : v3;
      const float og = (q4 == 3) ? v0 : (q4 == 2) ? v1 : (q4 == 1) ? v2 : v3;
      const float cn = sigm(fg) * c_st[e] + sigm(ig) * tanh_(gg);
      const float hn = sigm(og) * tanh_(cn);
      if (update) { c_st[e] = cn; h_st[e] = hn; }
      bf16_split(h_st[e], ph[e], plo[e]);
    }

    // publish fused 16B chunk (quad 0 only; all quads hold identical state)
    u32x4 vh16;
    vh16.x = (unsigned)ph[0]  | ((unsigned)ph[1]  << 16);
    vh16.y = (unsigned)ph[2]  | ((unsigned)ph[3]  << 16);
    vh16.z = (unsigned)plo[0] | ((unsigned)plo[1] << 16);
    vh16.w = (unsigned)plo[2] | ((unsigned)plo[3] << 16);
    const size_t chunk_off = ((size_t)uo * 128 + s) << 4;
    if (q4 == 0) store16_coh(wrc + chunk_off, vh16);

    // arrive: drain stores, WG-sync, post phase (own cache line)
    asm volatile("s_waitcnt vmcnt(0)" ::: "memory");
    __syncthreads();
    const unsigned phase = (unsigned)(t + 2);
    if (tid == 0)
      __hip_atomic_store((unsigned*)(arrb + (size_t)(sh * 64 + uo) * 128), phase,
                         __ATOMIC_RELAXED, SCOPE_AGENT);

    // off-critical-path: decoder log (plain store) + next x-part prefetch (into registers;
    // values survive the acquire fence below)
    if (t >= T_ && q4 == 0) {
      const int td = t - T_;
      *(u32x4*)(decb + ((((size_t)td * 64 + uo) * 128 + s) << 4)) = vh16;
    }
    f32x4 nx0, nx1, nx2;
    xpart(t + 1, nx0, nx1, nx2);

    // wait: 16 lanes poll 4 flag lines each (pipelined within one round trip)
    if (tid < 16) {
      const unsigned* f0 = (const unsigned*)(arrb + (size_t)(sh * 64 + tid * 4 + 0) * 128);
      const unsigned* f1 = (const unsigned*)(arrb + (size_t)(sh * 64 + tid * 4 + 1) * 128);
      const unsigned* f2 = (const unsigned*)(arrb + (size_t)(sh * 64 + tid * 4 + 2) * 128);
      const unsigned* f3 = (const unsigned*)(arrb + (size_t)(sh * 64 + tid * 4 + 3) * 128);
      bool ok;
      do {
        unsigned a = __hip_atomic_load(f0, __ATOMIC_RELAXED, SCOPE_AGENT);
        unsigned b = __hip_atomic_load(f1, __ATOMIC_RELAXED, SCOPE_AGENT);
        unsigned c = __hip_atomic_load(f2, __ATOMIC_RELAXED, SCOPE_AGENT);
        unsigned d = __hip_atomic_load(f3, __ATOMIC_RELAXED, SCOPE_AGENT);
        ok = (a >= phase) & (b >= phase) & (c >= phase) & (d >= phase);
      } while (!__all((int)ok));
    }
    __syncthreads();
    // acquire: invalidate L1/L2 copies so next step's sc0 loads refetch fresh data
    __builtin_amdgcn_fence(__ATOMIC_ACQUIRE, "agent");

    xa0 = nx0; xa1 = nx1; xa2 = nx2;
  }
}

// z[m][n] = relu(b1[n] + sum_k dec_h[m][k] * W1[n][k]),  m = td*128+s
__global__ __launch_bounds__(256) void mlp1(
    const char* __restrict__ decb,
    const float* __restrict__ W1, const float* __restrict__ b1,
    unsigned short* __restrict__ z_hi, unsigned short* __restrict__ z_lo)
{
  __shared__ unsigned short Ahi[32][264];
  __shared__ unsigned short Alo[32][264];
  __shared__ float bias_s[32];
  const int tid  = threadIdx.x;
  const int nblk = blockIdx.x & 7;
  const int mblk = blockIdx.x >> 3;     // = td
  const int n0   = nblk * 32;
  const int wave = tid >> 6, lane = tid & 63, q4 = lane >> 4, n15 = lane & 15;

  for (int e = tid; e < 32 * 256; e += 256) {
    const int row = e >> 8, k = e & 255;
    unsigned short h16, l16;
    bf16_split(W1[(n0 + row) * 256 + k], h16, l16);
    Ahi[row][k] = h16; Alo[row][k] = l16;
  }
  if (tid < 32) bias_s[tid] = b1[n0 + tid];
  __syncthreads();

  f32x4 acc[2][2];
  #pragma unroll
  for (int r = 0; r < 2; ++r)
    #pragma unroll
    for (int c = 0; c < 2; ++c)
      #pragma unroll
      for (int e = 0; e < 4; ++e) acc[r][c][e] = bias_s[16 * r + q4 * 4 + e];

  #pragma unroll
  for (int kh = 0; kh < 8; ++kh) {
    const int k0 = kh * 32 + q4 * 8;
    const bf16x8 ah0 = *(const bf16x8*)&Ahi[n15][k0];
    const bf16x8 ah1 = *(const bf16x8*)&Ahi[16 + n15][k0];
    const bf16x8 al0 = *(const bf16x8*)&Alo[n15][k0];
    const bf16x8 al1 = *(const bf16x8*)&Alo[16 + n15][k0];
    const int u0 = (kh * 4 + q4) * 2;
    #pragma unroll
    for (int c = 0; c < 2; ++c) {
      const int sloc = wave * 32 + c * 16 + n15;
      const char* base = decb + ((((size_t)mblk * 64 + u0) * 128 + sloc) << 4);
      const u32x4 A4 = *(const u32x4*)base;
      const u32x4 B4 = *(const u32x4*)(base + 2048);
      union { u32x4 q; bf16x8 v; } bh, bl;
      bh.q.x = A4.x; bh.q.y = A4.y; bh.q.z = B4.x; bh.q.w = B4.y;
      bl.q.x = A4.z; bl.q.y = A4.w; bl.q.z = B4.z; bl.q.w = B4.w;
      acc[0][c] = mf(ah0, bh.v, acc[0][c]);
      acc[1][c] = mf(ah1, bh.v, acc[1][c]);
      acc[0][c] = mf(ah0, bl.v, acc[0][c]);
      acc[1][c] = mf(ah1, bl.v, acc[1][c]);
      acc[0][c] = mf(al0, bh.v, acc[0][c]);
      acc[1][c] = mf(al1, bh.v, acc[1][c]);
    }
  }

  #pragma unroll
  for (int r = 0; r < 2; ++r)
    #pragma unroll
    for (int c = 0; c < 2; ++c) {
      const int sloc = wave * 32 + c * 16 + n15;
      const int m = mblk * 128 + sloc;
      const int ng = n0 + 16 * r + q4 * 4;
      unsigned short hh[4], ll[4];
      #pragma unroll
      for (int e = 0; e < 4; ++e) {
        const float v = fmaxf(acc[r][c][e], 0.0f);
        bf16_split(v, hh[e], ll[e]);
      }
      uint2 uh2, ul2;
      uh2.x = (unsigned)hh[0] | ((unsigned)hh[1] << 16);
      uh2.y = (unsigned)hh[2] | ((unsigned)hh[3] << 16);
      ul2.x = (unsigned)ll[0] | ((unsigned)ll[1] << 16);
      ul2.y = (unsigned)ll[2] | ((unsigned)ll[3] << 16);
      *(uint2*)(z_hi + m * 256 + ng) = uh2;
      *(uint2*)(z_lo + m * 256 + ng) = ul2;
    }
}

// out[s][td][c] = b2[c] + sum_n z[m][n] * W2[c][n],  m = td*128+s
__global__ __launch_bounds__(256) void mlp2(
    const unsigned short* __restrict__ z_hi, const unsigned short* __restrict__ z_lo,
    const float* __restrict__ W2, const float* __restrict__ b2,
    float* __restrict__ out)
{
  __shared__ unsigned short Ahi[32][264];
  __shared__ unsigned short Alo[32][264];
  __shared__ float bias_s[32];
  const int tid  = threadIdx.x;
  const int cblk = blockIdx.x & 1;
  const int mblk = blockIdx.x >> 1;
  const int c0   = cblk * 32;
  const int wave = tid >> 6, lane = tid & 63, q4 = lane >> 4, n15 = lane & 15;

  for (int e = tid; e < 32 * 256; e += 256) {
    const int row = e >> 8, k = e & 255;
    unsigned short h16, l16;
    bf16_split(W2[(c0 + row) * 256 + k], h16, l16);
    Ahi[row][k] = h16; Alo[row][k] = l16;
  }
  if (tid < 32) bias_s[tid] = b2[c0 + tid];
  __syncthreads();

  f32x4 acc[2][2];
  #pragma unroll
  for (int r = 0; r < 2; ++r)
    #pragma unroll
    for (int c = 0; c < 2; ++c)
      #pragma unroll
      for (int e = 0; e < 4; ++e) acc[r][c][e] = bias_s[16 * r + q4 * 4 + e];

  #pragma unroll
  for (int kh = 0; kh < 8; ++kh) {
    const int k0 = kh * 32 + q4 * 8;
    const bf16x8 ah0 = *(const bf16x8*)&Ahi[n15][k0];
    const bf16x8 ah1 = *(const bf16x8*)&Ahi[16 + n15][k0];
    const bf16x8 al0 = *(const bf16x8*)&Alo[n15][k0];
    const bf16x8 al1 = *(const bf16x8*)&Alo[16 + n15][k0];
    #pragma unroll
    for (int c = 0; c < 2; ++c) {
      const int m = mblk * 128 + wave * 32 + c * 16 + n15;
      const bf16x8 bh = *(const bf16x8*)(z_hi + m * 256 + k0);
      const bf16x8 bl = *(const bf16x8*)(z_lo + m * 256 + k0);
      acc[0][c] = mf(ah0, bh, acc[0][c]);
      acc[1][c] = mf(ah1, bh, acc[1][c]);
      acc[0][c] = mf(ah0, bl, acc[0][c]);
      acc[1][c] = mf(ah1, bl, acc[1][c]);
      acc[0][c] = mf(al0, bh, acc[0][c]);
      acc[1][c] = mf(al1, bh, acc[1][c]);
    }
  }

  #pragma unroll
  for (int r = 0; r < 2; ++r)
    #pragma unroll
    for (int c = 0; c < 2; ++c) {
      const int m  = mblk * 128 + wave * 32 + c * 16 + n15;
      const int ss = m & 127;
      const int td = m >> 7;
      const int cg = c0 + 16 * r + q4 * 4;
      *(f32x4*)(out + ss * (DEC_ * C_) + td * C_ + cg) = acc[r][c];
    }
}

extern "C" void kernel_launch(void* const* d_in, const int* in_sizes, int n_in,
                              void* d_out, int out_size, void* d_ws, size_t ws_size,
                              hipStream_t stream) {
  (void)in_sizes; (void)n_in; (void)out_size;
  const float* x    = (const float*)d_in[0];
  const int*   lens = (const int*)d_in[1];
  // d_in[2] = out_lengths (constant 128), unused
  const float* W_ih = (const float*)d_in[3];
  const float* W_hh = (const float*)d_in[4];
  const float* b_ih = (const float*)d_in[5];
  const float* b_hh = (const float*)d_in[6];
  const float* W1   = (const float*)d_in[7];
  const float* b1   = (const float*)d_in[8];
  const float* W2   = (const float*)d_in[9];
  const float* b2   = (const float*)d_in[10];
  float* out = (float*)d_out;

  char* ws8  = (char*)d_ws;
  char* arrb = ws8;                      // 16 KB flag region (128 B per WG)
  char* hxc  = ws8 + 16384;              // 2 x 128 KB parity exchange buffers

  // use_xs layout: x planes live during rnn4; z aliases the (then-dead) x_hi region.
  const size_t NEED_XS = 50610176ull;
  const int use_xs = (ws_size >= NEED_XS) ? 1 : 0;

  unsigned short* x_hi; unsigned short* x_lo; char* decb;
  unsigned short* z_hi; unsigned short* z_lo;
  if (use_xs) {
    x_hi = (unsigned short*)(ws8 + 278528);
    x_lo = x_hi + (size_t)B_ * T_ * I_;              // +16 MB
    decb = ws8 + 33832960;                           // 16 MB
    z_hi = (unsigned short*)(ws8 + 278528);          // alias x_hi (dead after rnn4)
    z_lo = z_hi + (size_t)DEC_ * B_ * H_;            // +8 MB, still inside x_hi
  } else {
    x_hi = nullptr; x_lo = nullptr;
    decb = ws8 + 278528;
    z_hi = (unsigned short*)(ws8 + 278528 + 16777216);
    z_lo = z_hi + (size_t)DEC_ * B_ * H_;
  }

  (void)hipMemsetAsync(arrb, 0, 16384, stream);      // zero flag lines
  if (use_xs) {
    const int n4 = (B_ * T_ * I_) / 4;
    xsplit_k<<<(n4 + 255) / 256, 256, 0, stream>>>(x, x_hi, x_lo, n4);
  }
  rnn4<<<NWG, 256, 0, stream>>>(x, x_hi, x_lo, use_xs, lens,
                                W_ih, W_hh, b_ih, b_hh,
                                arrb, hxc, decb);
  mlp1<<<1024, 256, 0, stream>>>(decb, W1, b1, z_hi, z_lo);
  mlp2<<<256, 256, 0, stream>>>(z_hi, z_lo, W2, b2, out);
}

// Round 5
// 4452.281 us; speedup vs baseline: 1.9721x; 1.9721x over previous
//
#include <hip/hip_runtime.h>

#define B_    128
#define T_    1024
#define I_    64
#define H_    256
#define DEC_  128
#define C_    64
#define NWG   128          // 64 unit-slices x 2 sample halves
#define KTOT  320          // K = H (256) + I (64)
#define LDK   328          // padded LDS stride (ushorts), init staging only
#define STEPS (T_ + DEC_)
#define RING  32           // h-version ring slots
#define SAFE  24           // wave-barrier period (skew bound < RING-2)

typedef short bf16x8 __attribute__((ext_vector_type(8)));
typedef float f32x4  __attribute__((ext_vector_type(4)));
typedef unsigned u32x4 __attribute__((ext_vector_type(4)));

#define SCOPE_AGENT __HIP_MEMORY_SCOPE_AGENT
#define TAGM 0x00010001u

__device__ __forceinline__ f32x4 mf(bf16x8 a, bf16x8 b, f32x4 c) {
  return __builtin_amdgcn_mfma_f32_16x16x32_bf16(a, b, c, 0, 0, 0);
}

// coherence-point 16B ops (bypass per-XCD L2 via sc1); single-instruction = atomic snapshot
__device__ __forceinline__ u32x4 load16_coh(const void* p) {
  u32x4 r;
  asm volatile("global_load_dwordx4 %0, %1, off sc0 sc1" : "=v"(r) : "v"(p) : "memory");
  return r;
}
__device__ __forceinline__ void store16_coh(void* p, u32x4 v) {
  asm volatile("global_store_dwordx4 %0, %1, off sc0 sc1" :: "v"(p), "v"(v) : "memory");
}

// round-to-nearest-even split of f32 into bf16 hi + bf16 lo (v ~= hi + lo)
__device__ __forceinline__ void bf16_split(float v, unsigned short& hi, unsigned short& lo) {
  unsigned u = __float_as_uint(v);
  unsigned r = (u + 0x7fffu + ((u >> 16) & 1u)) & 0xffff0000u;
  hi = (unsigned short)(r >> 16);
  float fl = v - __uint_as_float(r);
  unsigned u2 = __float_as_uint(fl);
  unsigned r2 = (u2 + 0x7fffu + ((u2 >> 16) & 1u)) & 0xffff0000u;
  lo = (unsigned short)(r2 >> 16);
}

__device__ __forceinline__ float sigm(float v) { return 1.0f / (1.0f + __expf(-v)); }
__device__ __forceinline__ float tanh_(float v) {
  float e = __expf(-2.0f * fabsf(v));
  float t = (1.0f - e) / (1.0f + e);
  return (v >= 0.0f) ? t : -t;
}

// x (f32) -> bf16 hi/lo planes
__global__ __launch_bounds__(256) void xsplit_k(const float* __restrict__ x,
                                                unsigned short* __restrict__ xh,
                                                unsigned short* __restrict__ xl, int n4) {
  const int i = blockIdx.x * 256 + threadIdx.x;
  if (i >= n4) return;
  const float4 v = ((const float4*)x)[i];
  unsigned short h[4], l[4];
  bf16_split(v.x, h[0], l[0]);
  bf16_split(v.y, h[1], l[1]);
  bf16_split(v.z, h[2], l[2]);
  bf16_split(v.w, h[3], l[3]);
  uint2 uh, ul;
  uh.x = (unsigned)h[0] | ((unsigned)h[1] << 16);
  uh.y = (unsigned)h[2] | ((unsigned)h[3] << 16);
  ul.x = (unsigned)l[0] | ((unsigned)l[1] << 16);
  ul.y = (unsigned)l[2] | ((unsigned)l[3] << 16);
  ((uint2*)xh)[i] = uh;
  ((uint2*)xl)[i] = ul;
}

// Ring slot (128 KB): chunk(u, s) = 16 B at ((u*128 + s)*16):
//   bytes 0-7 hi bf16 of units u*4..u*4+3, bytes 8-15 lo (LSB of each lo word = gen tag bit).
// Version v of h lives in slot v%RING with 4-bit gen (v>>5)&15 embedded in lo LSBs.
// Reader of version v polls its 16 chunks until all gens match -> poll IS the data load.
// Ring pre-memset to 0xFF (gen 15) so poisoned/unwritten chunks never false-match gen 0.
__global__ __launch_bounds__(256, 1) void rnn5(
    const float* __restrict__ x,
    const unsigned short* __restrict__ x_hi,
    const unsigned short* __restrict__ x_lo,
    const int use_xs,
    const int* __restrict__ lengths,
    const float* __restrict__ W_ih, const float* __restrict__ W_hh,
    const float* __restrict__ b_ih, const float* __restrict__ b_hh,
    char* __restrict__ arrb,
    char* __restrict__ ring,
    char* __restrict__ decb)
{
  __shared__ unsigned short Whi[16][LDK];   // init staging only
  __shared__ unsigned short Wlo[16][LDK];

  const int tid  = threadIdx.x;
  const int g    = blockIdx.x;
  const int uo   = g >> 1;
  const int sh   = g & 1;
  const int j0   = uo * 4;
  const int wave = tid >> 6;
  const int lane = tid & 63;
  const int q4   = lane >> 4;
  const int n15  = lane & 15;
  const int s    = sh * 64 + wave * 16 + n15;

  // ---- init: stage split weights into LDS, then lift fragments into VGPRs ----
  for (int e = tid; e < 16 * KTOT; e += 256) {
    const int row = e / KTOT;
    const int k   = e - row * KTOT;
    const int grow = (row >> 2) * H_ + j0 + (row & 3);
    const float v = (k < H_) ? W_hh[grow * H_ + k] : W_ih[grow * I_ + (k - H_)];
    unsigned short h16, l16; bf16_split(v, h16, l16);
    Whi[row][k] = h16; Wlo[row][k] = l16;
  }
  __syncthreads();

  bf16x8 Ah[10], Al[10];                 // weight fragments, resident in VGPRs
  #pragma unroll
  for (int kh = 0; kh < 8; ++kh) {
    const int k0 = kh * 32 + q4 * 8;
    Ah[kh] = *(const bf16x8*)&Whi[n15][k0];
    Al[kh] = *(const bf16x8*)&Wlo[n15][k0];
  }
  #pragma unroll
  for (int kx = 0; kx < 2; ++kx) {
    const int k0 = H_ + kx * 32 + q4 * 8;
    Ah[8 + kx] = *(const bf16x8*)&Whi[n15][k0];
    Al[8 + kx] = *(const bf16x8*)&Wlo[n15][k0];
  }
  float bias4[4];
  #pragma unroll
  for (int e = 0; e < 4; ++e) {
    const int grow = q4 * H_ + j0 + e;   // gate = q4, unit = e
    bias4[e] = b_ih[grow] + b_hh[grow];
  }

  const int len_s = lengths[s];

  // publish version 0 (zeros, gen 0) to slot 0 -- readers poll, no barrier needed
  if (tid < 64) {
    const int sz = sh * 64 + tid;
    u32x4 z; z.x = 0u; z.y = 0u; z.z = 0u; z.w = 0u;
    store16_coh(ring + (((size_t)uo * 128 + sz) << 4), z);
  }

  // x-part gate prefetch (independent of h); a0 seeded with bias
  auto xpart = [&](int t, f32x4& a0, f32x4& a1, f32x4& a2) {
    #pragma unroll
    for (int e = 0; e < 4; ++e) { a0[e] = bias4[e]; a1[e] = 0.f; a2[e] = 0.f; }
    if (t >= T_) return;
    #pragma unroll
    for (int kx = 0; kx < 2; ++kx) {
      bf16x8 bh, bl;
      if (use_xs) {
        const int xo = (s * T_ + t) * I_ + kx * 32 + q4 * 8;
        bh = *(const bf16x8*)(x_hi + xo);
        bl = *(const bf16x8*)(x_lo + xo);
      } else {
        const float* xp = x + ((size_t)s * T_ + t) * I_ + kx * 32 + q4 * 8;
        const float4 xa = *(const float4*)xp;
        const float4 xb = *(const float4*)(xp + 4);
        union { bf16x8 v; unsigned short u[8]; } bxh, bxl;
        float xv[8] = {xa.x, xa.y, xa.z, xa.w, xb.x, xb.y, xb.z, xb.w};
        #pragma unroll
        for (int e2 = 0; e2 < 8; ++e2) bf16_split(xv[e2], bxh.u[e2], bxl.u[e2]);
        bh = bxh.v; bl = bxl.v;
      }
      a0 = mf(Ah[8 + kx], bh, a0);
      a1 = mf(Ah[8 + kx], bl, a1);
      a2 = mf(Al[8 + kx], bh, a2);
    }
  };

  f32x4 xa0, xa1, xa2;
  xpart(0, xa0, xa1, xa2);

  float c_st[4] = {0.f, 0.f, 0.f, 0.f};
  float h_st[4] = {0.f, 0.f, 0.f, 0.f};

  for (int t = 0; t < STEPS; ++t) {
    const char* rslot = ring + (size_t)(t & (RING - 1)) * 131072;
    const unsigned gexp = (unsigned)((t >> 5) & 15);
    const unsigned ez = (gexp & 1u) | (((gexp >> 1) & 1u) << 16);
    const unsigned ew = ((gexp >> 2) & 1u) | (((gexp >> 3) & 1u) << 16);

    // poll-load: re-issue all 16 chunks until every gen tag matches (poll IS the read)
    u32x4 d0,d1,d2,d3,d4,d5,d6,d7,d8,d9,d10,d11,d12,d13,d14,d15;
    for (;;) {
#define LD_KH(i, DA, DB) { \
      const char* _b = rslot + (((size_t)(((i) * 8 + (q4 << 1)) * 128 + s)) << 4); \
      DA = load16_coh(_b); DB = load16_coh(_b + 2048); }
      LD_KH(0, d0,  d1)  LD_KH(1, d2,  d3)  LD_KH(2, d4,  d5)  LD_KH(3, d6,  d7)
      LD_KH(4, d8,  d9)  LD_KH(5, d10, d11) LD_KH(6, d12, d13) LD_KH(7, d14, d15)
#undef LD_KH
      asm volatile("s_waitcnt vmcnt(0)"
        : "+v"(d0),"+v"(d1),"+v"(d2),"+v"(d3),"+v"(d4),"+v"(d5),"+v"(d6),"+v"(d7),
          "+v"(d8),"+v"(d9),"+v"(d10),"+v"(d11),"+v"(d12),"+v"(d13),"+v"(d14),"+v"(d15)
        :: "memory");
      unsigned ok = 1u;
#define CK(D) ok &= (unsigned)((D.z & TAGM) == ez) & (unsigned)((D.w & TAGM) == ew);
      CK(d0) CK(d1) CK(d2) CK(d3) CK(d4) CK(d5) CK(d6) CK(d7)
      CK(d8) CK(d9) CK(d10) CK(d11) CK(d12) CK(d13) CK(d14) CK(d15)
#undef CK
      if (__all((int)ok)) break;
      __builtin_amdgcn_s_sleep(1);
    }

    f32x4 a0 = xa0, a1 = xa1, a2 = xa2;
#define MM_KH(i, DA, DB) { \
    union { u32x4 q; bf16x8 v; } _h, _l; \
    _h.q.x = DA.x; _h.q.y = DA.y; _h.q.z = DB.x; _h.q.w = DB.y; \
    _l.q.x = DA.z; _l.q.y = DA.w; _l.q.z = DB.z; _l.q.w = DB.w; \
    a0 = mf(Ah[i], _h.v, a0); a1 = mf(Ah[i], _l.v, a1); a2 = mf(Al[i], _h.v, a2); }
    MM_KH(0, d0,  d1)  MM_KH(1, d2,  d3)  MM_KH(2, d4,  d5)  MM_KH(3, d6,  d7)
    MM_KH(4, d8,  d9)  MM_KH(5, d10, d11) MM_KH(6, d12, d13) MM_KH(7, d14, d15)
#undef MM_KH

    // gate combine: gather i,f,g,o across quads via shfl_xor
    unsigned short ph[4], plo[4];
    const bool update = (t < T_) ? (t < len_s) : true;
    const unsigned gnxt = (unsigned)(((t + 1) >> 5) & 15);
    #pragma unroll
    for (int e = 0; e < 4; ++e) {
      const float v0 = a0[e] + a1[e] + a2[e];
      const float v1 = __shfl_xor(v0, 16, 64);
      const float v2 = __shfl_xor(v0, 32, 64);
      const float v3 = __shfl_xor(v1, 32, 64);
      const float ig = (q4 == 0) ? v0 : (q4 == 1) ? v1 : (q4 == 2) ? v2 : v3;
      const float fg = (q4 == 1) ? v0 : (q4 == 0) ? v1 : (q4 == 3) ? v2 : v3;
      const float gg = (q4 == 2) ? v0 : (q4 == 3) ? v1 : (q4 == 0) ? v2 : v3;
      const float og = (q4 == 3) ? v0 : (q4 == 2) ? v1 : (q4 == 1) ? v2 : v3;
      const float cn = sigm(fg) * c_st[e] + sigm(ig) * tanh_(gg);
      const float hn = sigm(og) * tanh_(cn);
      if (update) { c_st[e] = cn; h_st[e] = hn; }
      bf16_split(h_st[e], ph[e], plo[e]);
      plo[e] = (unsigned short)((plo[e] & 0xFFFEu) | ((gnxt >> e) & 1u));  // embed gen bit
    }

    // publish fused 16B chunk with embedded tag (single store = atomic snapshot; no ack wait)
    u32x4 vh16;
    vh16.x = (unsigned)ph[0]  | ((unsigned)ph[1]  << 16);
    vh16.y = (unsigned)ph[2]  | ((unsigned)ph[3]  << 16);
    vh16.z = (unsigned)plo[0] | ((unsigned)plo[1] << 16);
    vh16.w = (unsigned)plo[2] | ((unsigned)plo[3] << 16);
    const size_t chunk_off = ((size_t)uo * 128 + s) << 4;
    if (q4 == 0)
      store16_coh(ring + (size_t)((t + 1) & (RING - 1)) * 131072 + chunk_off, vh16);

    // off-critical-path: decoder log (plain store) + next x-part prefetch
    if (t >= T_ && q4 == 0) {
      const int td = t - T_;
      *(u32x4*)(decb + ((((size_t)td * 64 + uo) * 128 + s) << 4)) = vh16;
    }
    xpart(t + 1, xa0, xa1, xa2);

    // periodic wave-level barrier: bounds skew < SAFE so ring slots are never
    // overwritten while a lagging reader still needs them (SAFE <= RING-2)
    if ((t % SAFE) == (SAFE - 1)) {
      asm volatile("s_waitcnt vmcnt(0)" ::: "memory");
      const unsigned ep = (unsigned)(t + 1);
      const int wid = g * 4 + wave;          // 0..511
      if (lane == 0)
        __hip_atomic_store((unsigned*)(arrb + (size_t)wid * 128), ep,
                           __ATOMIC_RELAXED, SCOPE_AGENT);
      bool okb;
      do {
        unsigned mn = ~0u;
        #pragma unroll
        for (int j = 0; j < 8; ++j) {
          unsigned v = __hip_atomic_load(
              (const unsigned*)(arrb + (size_t)(lane * 8 + j) * 128),
              __ATOMIC_RELAXED, SCOPE_AGENT);
          mn = (v < mn) ? v : mn;
        }
        okb = (mn >= ep);
      } while (!__all((int)okb));
    }
  }
}

// z[m][n] = relu(b1[n] + sum_k dec_h[m][k] * W1[n][k]),  m = td*128+s
__global__ __launch_bounds__(256) void mlp1(
    const char* __restrict__ decb,
    const float* __restrict__ W1, const float* __restrict__ b1,
    unsigned short* __restrict__ z_hi, unsigned short* __restrict__ z_lo)
{
  __shared__ unsigned short Ahi[32][264];
  __shared__ unsigned short Alo[32][264];
  __shared__ float bias_s[32];
  const int tid  = threadIdx.x;
  const int nblk = blockIdx.x & 7;
  const int mblk = blockIdx.x >> 3;     // = td
  const int n0   = nblk * 32;
  const int wave = tid >> 6, lane = tid & 63, q4 = lane >> 4, n15 = lane & 15;

  for (int e = tid; e < 32 * 256; e += 256) {
    const int row = e >> 8, k = e & 255;
    unsigned short h16, l16;
    bf16_split(W1[(n0 + row) * 256 + k], h16, l16);
    Ahi[row][k] = h16; Alo[row][k] = l16;
  }
  if (tid < 32) bias_s[tid] = b1[n0 + tid];
  __syncthreads();

  f32x4 acc[2][2];
  #pragma unroll
  for (int r = 0; r < 2; ++r)
    #pragma unroll
    for (int c = 0; c < 2; ++c)
      #pragma unroll
      for (int e = 0; e < 4; ++e) acc[r][c][e] = bias_s[16 * r + q4 * 4 + e];

  #pragma unroll
  for (int kh = 0; kh < 8; ++kh) {
    const int k0 = kh * 32 + q4 * 8;
    const bf16x8 ah0 = *(const bf16x8*)&Ahi[n15][k0];
    const bf16x8 ah1 = *(const bf16x8*)&Ahi[16 + n15][k0];
    const bf16x8 al0 = *(const bf16x8*)&Alo[n15][k0];
    const bf16x8 al1 = *(const bf16x8*)&Alo[16 + n15][k0];
    const int u0 = (kh * 4 + q4) * 2;
    #pragma unroll
    for (int c = 0; c < 2; ++c) {
      const int sloc = wave * 32 + c * 16 + n15;
      const char* base = decb + ((((size_t)mblk * 64 + u0) * 128 + sloc) << 4);
      const u32x4 A4 = *(const u32x4*)base;
      const u32x4 B4 = *(const u32x4*)(base + 2048);
      union { u32x4 q; bf16x8 v; } bh, bl;
      bh.q.x = A4.x; bh.q.y = A4.y; bh.q.z = B4.x; bh.q.w = B4.y;
      bl.q.x = A4.z; bl.q.y = A4.w; bl.q.z = B4.z; bl.q.w = B4.w;
      acc[0][c] = mf(ah0, bh.v, acc[0][c]);
      acc[1][c] = mf(ah1, bh.v, acc[1][c]);
      acc[0][c] = mf(ah0, bl.v, acc[0][c]);
      acc[1][c] = mf(ah1, bl.v, acc[1][c]);
      acc[0][c] = mf(al0, bh.v, acc[0][c]);
      acc[1][c] = mf(al1, bh.v, acc[1][c]);
    }
  }

  #pragma unroll
  for (int r = 0; r < 2; ++r)
    #pragma unroll
    for (int c = 0; c < 2; ++c) {
      const int sloc = wave * 32 + c * 16 + n15;
      const int m = mblk * 128 + sloc;
      const int ng = n0 + 16 * r + q4 * 4;
      unsigned short hh[4], ll[4];
      #pragma unroll
      for (int e = 0; e < 4; ++e) {
        const float v = fmaxf(acc[r][c][e], 0.0f);
        bf16_split(v, hh[e], ll[e]);
      }
      uint2 uh2, ul2;
      uh2.x = (unsigned)hh[0] | ((unsigned)hh[1] << 16);
      uh2.y = (unsigned)hh[2] | ((unsigned)hh[3] << 16);
      ul2.x = (unsigned)ll[0] | ((unsigned)ll[1] << 16);
      ul2.y = (unsigned)ll[2] | ((unsigned)ll[3] << 16);
      *(uint2*)(z_hi + m * 256 + ng) = uh2;
      *(uint2*)(z_lo + m * 256 + ng) = ul2;
    }
}

// out[s][td][c] = b2[c] + sum_n z[m][n] * W2[c][n],  m = td*128+s
__global__ __launch_bounds__(256) void mlp2(
    const unsigned short* __restrict__ z_hi, const unsigned short* __restrict__ z_lo,
    const float* __restrict__ W2, const float* __restrict__ b2,
    float* __restrict__ out)
{
  __shared__ unsigned short Ahi[32][264];
  __shared__ unsigned short Alo[32][264];
  __shared__ float bias_s[32];
  const int tid  = threadIdx.x;
  const int cblk = blockIdx.x & 1;
  const int mblk = blockIdx.x >> 1;
  const int c0   = cblk * 32;
  const int wave = tid >> 6, lane = tid & 63, q4 = lane >> 4, n15 = lane & 15;

  for (int e = tid; e < 32 * 256; e += 256) {
    const int row = e >> 8, k = e & 255;
    unsigned short h16, l16;
    bf16_split(W2[(c0 + row) * 256 + k], h16, l16);
    Ahi[row][k] = h16; Alo[row][k] = l16;
  }
  if (tid < 32) bias_s[tid] = b2[c0 + tid];
  __syncthreads();

  f32x4 acc[2][2];
  #pragma unroll
  for (int r = 0; r < 2; ++r)
    #pragma unroll
    for (int c = 0; c < 2; ++c)
      #pragma unroll
      for (int e = 0; e < 4; ++e) acc[r][c][e] = bias_s[16 * r + q4 * 4 + e];

  #pragma unroll
  for (int kh = 0; kh < 8; ++kh) {
    const int k0 = kh * 32 + q4 * 8;
    const bf16x8 ah0 = *(const bf16x8*)&Ahi[n15][k0];
    const bf16x8 ah1 = *(const bf16x8*)&Ahi[16 + n15][k0];
    const bf16x8 al0 = *(const bf16x8*)&Alo[n15][k0];
    const bf16x8 al1 = *(const bf16x8*)&Alo[16 + n15][k0];
    #pragma unroll
    for (int c = 0; c < 2; ++c) {
      const int m = mblk * 128 + wave * 32 + c * 16 + n15;
      const bf16x8 bh = *(const bf16x8*)(z_hi + m * 256 + k0);
      const bf16x8 bl = *(const bf16x8*)(z_lo + m * 256 + k0);
      acc[0][c] = mf(ah0, bh, acc[0][c]);
      acc[1][c] = mf(ah1, bh, acc[1][c]);
      acc[0][c] = mf(ah0, bl, acc[0][c]);
      acc[1][c] = mf(ah1, bl, acc[1][c]);
      acc[0][c] = mf(al0, bh, acc[0][c]);
      acc[1][c] = mf(al1, bh, acc[1][c]);
    }
  }

  #pragma unroll
  for (int r = 0; r < 2; ++r)
    #pragma unroll
    for (int c = 0; c < 2; ++c) {
      const int m  = mblk * 128 + wave * 32 + c * 16 + n15;
      const int ss = m & 127;
      const int td = m >> 7;
      const int cg = c0 + 16 * r + q4 * 4;
      *(f32x4*)(out + ss * (DEC_ * C_) + td * C_ + cg) = acc[r][c];
    }
}

extern "C" void kernel_launch(void* const* d_in, const int* in_sizes, int n_in,
                              void* d_out, int out_size, void* d_ws, size_t ws_size,
                              hipStream_t stream) {
  (void)in_sizes; (void)n_in; (void)out_size;
  const float* x    = (const float*)d_in[0];
  const int*   lens = (const int*)d_in[1];
  // d_in[2] = out_lengths (constant 128), unused
  const float* W_ih = (const float*)d_in[3];
  const float* W_hh = (const float*)d_in[4];
  const float* b_ih = (const float*)d_in[5];
  const float* b_hh = (const float*)d_in[6];
  const float* W1   = (const float*)d_in[7];
  const float* b1   = (const float*)d_in[8];
  const float* W2   = (const float*)d_in[9];
  const float* b2   = (const float*)d_in[10];
  float* out = (float*)d_out;

  char* ws8  = (char*)d_ws;
  char* arrb = ws8;                           // 64 KB wave-flag region (128 B per wave)
  char* ring = ws8 + 65536;                   // RING x 128 KB = 4 MB version ring
  char* decb = ws8 + 65536 + (size_t)RING * 131072;   // 16 MB decoder h log

  const size_t decb_end = 65536 + (size_t)RING * 131072 + 16777216ull;
  const size_t NEED_XS  = decb_end + 2ull * 16777216ull;   // + x hi/lo planes
  const int use_xs = (ws_size >= NEED_XS) ? 1 : 0;

  unsigned short* x_hi; unsigned short* x_lo;
  unsigned short* z_hi; unsigned short* z_lo;
  if (use_xs) {
    x_hi = (unsigned short*)(ws8 + decb_end);
    x_lo = x_hi + (size_t)B_ * T_ * I_;
    z_hi = (unsigned short*)(ws8 + decb_end);        // alias x_hi (dead after rnn5)
    z_lo = z_hi + (size_t)DEC_ * B_ * H_;
  } else {
    x_hi = nullptr; x_lo = nullptr;
    z_hi = (unsigned short*)(ws8 + decb_end);
    z_lo = z_hi + (size_t)DEC_ * B_ * H_;
  }

  (void)hipMemsetAsync(arrb, 0, 65536, stream);              // zero wave flags
  (void)hipMemsetAsync(ring, 0xFF, (size_t)RING * 131072, stream);  // gen-15 sentinel
  if (use_xs) {
    const int n4 = (B_ * T_ * I_) / 4;
    xsplit_k<<<(n4 + 255) / 256, 256, 0, stream>>>(x, x_hi, x_lo, n4);
  }
  rnn5<<<NWG, 256, 0, stream>>>(x, x_hi, x_lo, use_xs, lens,
                                W_ih, W_hh, b_ih, b_hh,
                                arrb, ring, decb);
  mlp1<<<1024, 256, 0, stream>>>(decb, W1, b1, z_hi, z_lo);
  mlp2<<<256, 256, 0, stream>>>(z_hi, z_lo, W2, b2, out);
}